// Round 4
// baseline (117.919 us; speedup 1.0000x reference)
//
#include <hip/hip_runtime.h>
#include <math.h>

#define Bb   2
#define Hh   56
#define Ww   56
#define Cc   256
#define NHh  8
#define HDd  32
#define KK   7
#define HWsz (Hh*Ww)
#define Mtot (Bb*Hh*Ww)   // 6272

typedef __bf16 bf16x8 __attribute__((ext_vector_type(8)));
typedef float  f32x4  __attribute__((ext_vector_type(4)));

// C[m,n] = sum_k A[m,k] * Wrow(n)[k]  (x @ W^T) via bf16 MFMA, fp32 accum.
__global__ __launch_bounds__(256) void gemm_bf16(
    const float* __restrict__ A, const float* __restrict__ W0,
    const float* __restrict__ W1, float* __restrict__ Cout,
    int Kdim, int N, int n_split, int scale_below, float scale,
    const float* __restrict__ bias)
{
    __shared__ __bf16 As[4096];
    __shared__ __bf16 Bs[4096];

    const int tid = threadIdx.x;
    const int m0  = blockIdx.y * 64;
    const int n0  = blockIdx.x * 64;

    const int mm = tid >> 2;
    const int q  = tid & 3;
    const float* arow = A + (size_t)(m0 + mm) * Kdim + q * 16;
    const int n_idx = n0 + mm;
    const float* brow = (n_idx < n_split ? W0 + (size_t)n_idx * Kdim
                                         : W1 + (size_t)(n_idx - n_split) * Kdim) + q * 16;

    const int ks_st  = q >> 1;
    const int sub_st = mm >> 4;
    const int row_st = mm & 15;
    const int c0_st  = (q & 1) * 2;
    const int blk_st = ks_st * 4 + sub_st;
    const int off0 = blk_st * 512 + row_st * 32 + ((c0_st ^ (row_st & 3)) * 8);
    const int off1 = blk_st * 512 + row_st * 32 + (((c0_st + 1) ^ (row_st & 3)) * 8);

    const int w    = tid >> 6;
    const int lane = tid & 63;
    const int fr_row = lane & 15;
    const int fr_c   = lane >> 4;
    const int fr_off = fr_row * 32 + ((fr_c ^ (fr_row & 3)) * 8);

    f32x4 acc[4] = {};

    for (int k0 = 0; k0 < Kdim; k0 += 64) {
        float4 a0 = *(const float4*)(arow + k0);
        float4 a1 = *(const float4*)(arow + k0 + 4);
        float4 a2 = *(const float4*)(arow + k0 + 8);
        float4 a3 = *(const float4*)(arow + k0 + 12);
        float4 b0 = *(const float4*)(brow + k0);
        float4 b1 = *(const float4*)(brow + k0 + 4);
        float4 b2 = *(const float4*)(brow + k0 + 8);
        float4 b3 = *(const float4*)(brow + k0 + 12);
        __syncthreads();
        bf16x8 av0 = { (__bf16)a0.x, (__bf16)a0.y, (__bf16)a0.z, (__bf16)a0.w,
                       (__bf16)a1.x, (__bf16)a1.y, (__bf16)a1.z, (__bf16)a1.w };
        bf16x8 av1 = { (__bf16)a2.x, (__bf16)a2.y, (__bf16)a2.z, (__bf16)a2.w,
                       (__bf16)a3.x, (__bf16)a3.y, (__bf16)a3.z, (__bf16)a3.w };
        bf16x8 bv0 = { (__bf16)b0.x, (__bf16)b0.y, (__bf16)b0.z, (__bf16)b0.w,
                       (__bf16)b1.x, (__bf16)b1.y, (__bf16)b1.z, (__bf16)b1.w };
        bf16x8 bv1 = { (__bf16)b2.x, (__bf16)b2.y, (__bf16)b2.z, (__bf16)b2.w,
                       (__bf16)b3.x, (__bf16)b3.y, (__bf16)b3.z, (__bf16)b3.w };
        *(bf16x8*)&As[off0] = av0;
        *(bf16x8*)&As[off1] = av1;
        *(bf16x8*)&Bs[off0] = bv0;
        *(bf16x8*)&Bs[off1] = bv1;
        __syncthreads();
        #pragma unroll
        for (int ks = 0; ks < 2; ++ks) {
            bf16x8 af = *(const bf16x8*)&As[(ks * 4 + w) * 512 + fr_off];
            #pragma unroll
            for (int n = 0; n < 4; ++n) {
                bf16x8 bfr = *(const bf16x8*)&Bs[(ks * 4 + n) * 512 + fr_off];
                acc[n] = __builtin_amdgcn_mfma_f32_16x16x32_bf16(af, bfr, acc[n], 0, 0, 0);
            }
        }
    }

    #pragma unroll
    for (int n = 0; n < 4; ++n) {
        const int gcol = n0 + n * 16 + fr_row;
        const float sc_ = (gcol < scale_below) ? scale : 1.f;
        const float bs_ = bias ? bias[gcol] : 0.f;
        #pragma unroll
        for (int r = 0; r < 4; ++r) {
            const int grow = m0 + w * 16 + fr_c * 4 + r;
            Cout[(size_t)grow * N + gcol] = acc[n][r] * sc_ + bs_;
        }
    }
}

// Neighborhood attention, 8x4 query tile per (b, head). 256 threads.
// thread = (q 0..31, r 0..7). K staged in LDS (140x32, stride 36), V prefetched
// to registers then written over K. Q read direct from global (L1 broadcast).
// LDS = 140*36*4 + 32*49*4 = 25.8 KB -> 5 blocks/CU (launch_bounds cap).
__global__ __launch_bounds__(256, 5) void nattn_84(
    const float* __restrict__ qkv, float* __restrict__ attn_out,
    float* __restrict__ attn_glob)
{
    __shared__ float Ks[140 * 36];   // K then V
    __shared__ float Ss[32 * 49];    // probs

    const int bx   = blockIdx.x;
    const int head = bx & 7;
    int t = bx >> 3;
    const int tj = t % 14; t /= 14;
    const int ti = t % 7;
    const int b  = t / 7;
    const int tid = threadIdx.x;

    int base_h = ti * 8 - 3; if (base_h < 0) base_h = 0; if (base_h > Hh - 14) base_h = Hh - 14;
    int base_w = tj * 4 - 3; if (base_w < 0) base_w = 0; if (base_w > Ww - 10) base_w = Ww - 10;

    const int pixb = b * HWsz;
    const int hoff = head * 32;

    // --- stage K to LDS; prefetch V to registers; load Q to registers ---
    #pragma unroll
    for (int it = 0; it < 5; ++it) {
        const int idx = tid + it * 256;
        if (idx < 1120) {
            const int p = idx >> 3, c = idx & 7;
            const int pix = pixb + (base_h + p / 10) * Ww + base_w + p % 10;
            *(float4*)&Ks[p * 36 + c * 4] =
                *(const float4*)&qkv[(size_t)pix * 768 + 256 + hoff + c * 4];
        }
    }

    const int q  = tid >> 3;         // query in tile
    const int r  = tid & 7;          // key phase
    const int qi = ti * 8 + (q >> 2);
    const int qj = tj * 4 + (q & 3);

    float4 qreg[8];
    {
        const float* qp = &qkv[(size_t)(pixb + qi * Ww + qj) * 768 + hoff];
        #pragma unroll
        for (int c = 0; c < 8; ++c) qreg[c] = *(const float4*)(qp + c * 4);
    }

    float4 vreg[5];
    #pragma unroll
    for (int it = 0; it < 5; ++it) {
        const int idx = tid + it * 256;
        if (idx < 1120) {
            const int p = idx >> 3, c = idx & 7;
            const int pix = pixb + (base_h + p / 10) * Ww + base_w + p % 10;
            vreg[it] = *(const float4*)&qkv[(size_t)pix * 768 + 512 + hoff + c * 4];
        }
    }
    __syncthreads();

    int ih0 = qi - 3; if (ih0 < 0) ih0 = 0; if (ih0 > Hh - 7) ih0 = Hh - 7;
    int iw0 = qj - 3; if (iw0 < 0) iw0 = 0; if (iw0 > Ww - 7) iw0 = Ww - 7;
    const int lh0 = ih0 - base_h, lw0 = iw0 - base_w;

    // --- QK ---
    float sc[7];
    float mx = -1e30f;
    #pragma unroll
    for (int tt = 0; tt < 7; ++tt) {
        const int k = r + 8 * tt;
        if (k < 49) {
            const int krow = (lh0 + k / 7) * 10 + lw0 + k % 7;
            const float* kp = &Ks[krow * 36];
            float acc = 0.f;
            #pragma unroll
            for (int c = 0; c < 8; ++c) {
                const float4 kv = *(const float4*)(kp + c * 4);
                acc += qreg[c].x * kv.x + qreg[c].y * kv.y
                     + qreg[c].z * kv.z + qreg[c].w * kv.w;
            }
            sc[tt] = acc;
            mx = fmaxf(mx, acc);
        }
    }
    mx = fmaxf(mx, __shfl_xor(mx, 1));
    mx = fmaxf(mx, __shfl_xor(mx, 2));
    mx = fmaxf(mx, __shfl_xor(mx, 4));
    float sum = 0.f;
    #pragma unroll
    for (int tt = 0; tt < 7; ++tt) {
        const int k = r + 8 * tt;
        if (k < 49) { sc[tt] = __expf(sc[tt] - mx); sum += sc[tt]; }
    }
    sum += __shfl_xor(sum, 1);
    sum += __shfl_xor(sum, 2);
    sum += __shfl_xor(sum, 4);
    const float inv = 1.f / sum;
    #pragma unroll
    for (int tt = 0; tt < 7; ++tt) {
        const int k = r + 8 * tt;
        if (k < 49) Ss[q * 49 + k] = sc[tt] * inv;
    }
    __syncthreads();   // all K reads + all prob writes done

    // --- V regs -> LDS (no global latency here); attn probs -> global ---
    #pragma unroll
    for (int it = 0; it < 5; ++it) {
        const int idx = tid + it * 256;
        if (idx < 1120) {
            const int p = idx >> 3, c = idx & 7;
            *(float4*)&Ks[p * 36 + c * 4] = vreg[it];
        }
    }
    const size_t agbase = (size_t)(b * NHh + head) * HWsz;
    for (int idx = tid; idx < 32 * 49; idx += 256) {
        const int qq = idx / 49, k = idx - qq * 49;
        attn_glob[(agbase + (ti * 8 + (qq >> 2)) * Ww + tj * 4 + (qq & 3)) * 49 + k]
            = Ss[qq * 49 + k];
    }
    __syncthreads();

    // --- PV: thread (q, r) owns dims d = 4r .. 4r+3 ---
    const int d0 = r * 4;
    float4 a0 = {0, 0, 0, 0};
    #pragma unroll
    for (int k = 0; k < 49; ++k) {
        const float pr = Ss[q * 49 + k];
        const int vrow = (lh0 + k / 7) * 10 + lw0 + k % 7;
        const float4 v0 = *(const float4*)&Ks[vrow * 36 + d0];
        a0.x += pr * v0.x; a0.y += pr * v0.y; a0.z += pr * v0.z; a0.w += pr * v0.w;
    }
    float* op = attn_out + (size_t)(pixb + qi * Ww + qj) * 256 + hoff + d0;
    *(float4*)op = a0;
}

extern "C" void kernel_launch(void* const* d_in, const int* in_sizes, int n_in,
                              void* d_out, int out_size, void* d_ws, size_t ws_size,
                              hipStream_t stream)
{
    const float* x      = (const float*)d_in[0];
    const float* w_qk   = (const float*)d_in[1];
    const float* w_v    = (const float*)d_in[2];
    const float* w_proj = (const float*)d_in[3];
    const float* b_proj = (const float*)d_in[4];

    float* out       = (float*)d_out;                    // chunk 0: (B,H,W,C)
    float* attn_glob = out + (size_t)Mtot * Cc;          // chunk 1: (B,NH,H,W,49)

    float* qkv_ws  = (float*)d_ws;                       // M x 768 (q|k|v)
    float* attn_ws = qkv_ws + (size_t)Mtot * 768;        // M x 256

    const float scale = 0.17677669529663687f;            // HD^-0.5

    gemm_bf16<<<dim3(768 / 64, Mtot / 64), 256, 0, stream>>>(
        x, w_qk, w_v, qkv_ws, Cc, 768, 512, 256, scale, nullptr);

    nattn_84<<<Bb * 7 * 14 * NHh, 256, 0, stream>>>(qkv_ws, attn_ws, attn_glob);

    gemm_bf16<<<dim3(256 / 64, Mtot / 64), 256, 0, stream>>>(
        attn_ws, w_proj, w_proj, out, Cc, Cc, 1 << 30, 0, 1.f, b_proj);
}

// Round 5
// 113.162 us; speedup vs baseline: 1.0420x; 1.0420x over previous
//
#include <hip/hip_runtime.h>
#include <math.h>

#define Bb   2
#define Hh   56
#define Ww   56
#define Cc   256
#define NHh  8
#define HDd  32
#define KK   7
#define HWsz (Hh*Ww)
#define Mtot (Bb*Hh*Ww)   // 6272

typedef __bf16 bf16x8 __attribute__((ext_vector_type(8)));
typedef __bf16 bf16x4 __attribute__((ext_vector_type(4)));
typedef float  f32x4  __attribute__((ext_vector_type(4)));

// C[m,n] = sum_k A[m,k] * Wrow(n)[k]  (x @ W^T) via bf16 MFMA, fp32 accum.
__global__ __launch_bounds__(256) void gemm_bf16(
    const float* __restrict__ A, const float* __restrict__ W0,
    const float* __restrict__ W1, float* __restrict__ Cout,
    int Kdim, int N, int n_split, int scale_below, float scale,
    const float* __restrict__ bias)
{
    __shared__ __bf16 As[4096];
    __shared__ __bf16 Bs[4096];

    const int tid = threadIdx.x;
    const int m0  = blockIdx.y * 64;
    const int n0  = blockIdx.x * 64;

    const int mm = tid >> 2;
    const int q  = tid & 3;
    const float* arow = A + (size_t)(m0 + mm) * Kdim + q * 16;
    const int n_idx = n0 + mm;
    const float* brow = (n_idx < n_split ? W0 + (size_t)n_idx * Kdim
                                         : W1 + (size_t)(n_idx - n_split) * Kdim) + q * 16;

    const int ks_st  = q >> 1;
    const int sub_st = mm >> 4;
    const int row_st = mm & 15;
    const int c0_st  = (q & 1) * 2;
    const int blk_st = ks_st * 4 + sub_st;
    const int off0 = blk_st * 512 + row_st * 32 + ((c0_st ^ (row_st & 3)) * 8);
    const int off1 = blk_st * 512 + row_st * 32 + (((c0_st + 1) ^ (row_st & 3)) * 8);

    const int w    = tid >> 6;
    const int lane = tid & 63;
    const int fr_row = lane & 15;
    const int fr_c   = lane >> 4;
    const int fr_off = fr_row * 32 + ((fr_c ^ (fr_row & 3)) * 8);

    f32x4 acc[4] = {};

    for (int k0 = 0; k0 < Kdim; k0 += 64) {
        float4 a0 = *(const float4*)(arow + k0);
        float4 a1 = *(const float4*)(arow + k0 + 4);
        float4 a2 = *(const float4*)(arow + k0 + 8);
        float4 a3 = *(const float4*)(arow + k0 + 12);
        float4 b0 = *(const float4*)(brow + k0);
        float4 b1 = *(const float4*)(brow + k0 + 4);
        float4 b2 = *(const float4*)(brow + k0 + 8);
        float4 b3 = *(const float4*)(brow + k0 + 12);
        __syncthreads();
        bf16x8 av0 = { (__bf16)a0.x, (__bf16)a0.y, (__bf16)a0.z, (__bf16)a0.w,
                       (__bf16)a1.x, (__bf16)a1.y, (__bf16)a1.z, (__bf16)a1.w };
        bf16x8 av1 = { (__bf16)a2.x, (__bf16)a2.y, (__bf16)a2.z, (__bf16)a2.w,
                       (__bf16)a3.x, (__bf16)a3.y, (__bf16)a3.z, (__bf16)a3.w };
        bf16x8 bv0 = { (__bf16)b0.x, (__bf16)b0.y, (__bf16)b0.z, (__bf16)b0.w,
                       (__bf16)b1.x, (__bf16)b1.y, (__bf16)b1.z, (__bf16)b1.w };
        bf16x8 bv1 = { (__bf16)b2.x, (__bf16)b2.y, (__bf16)b2.z, (__bf16)b2.w,
                       (__bf16)b3.x, (__bf16)b3.y, (__bf16)b3.z, (__bf16)b3.w };
        *(bf16x8*)&As[off0] = av0;
        *(bf16x8*)&As[off1] = av1;
        *(bf16x8*)&Bs[off0] = bv0;
        *(bf16x8*)&Bs[off1] = bv1;
        __syncthreads();
        #pragma unroll
        for (int ks = 0; ks < 2; ++ks) {
            bf16x8 af = *(const bf16x8*)&As[(ks * 4 + w) * 512 + fr_off];
            #pragma unroll
            for (int n = 0; n < 4; ++n) {
                bf16x8 bfr = *(const bf16x8*)&Bs[(ks * 4 + n) * 512 + fr_off];
                acc[n] = __builtin_amdgcn_mfma_f32_16x16x32_bf16(af, bfr, acc[n], 0, 0, 0);
            }
        }
    }

    #pragma unroll
    for (int n = 0; n < 4; ++n) {
        const int gcol = n0 + n * 16 + fr_row;
        const float sc_ = (gcol < scale_below) ? scale : 1.f;
        const float bs_ = bias ? bias[gcol] : 0.f;
        #pragma unroll
        for (int r = 0; r < 4; ++r) {
            const int grow = m0 + w * 16 + fr_c * 4 + r;
            Cout[(size_t)grow * N + gcol] = acc[n][r] * sc_ + bs_;
        }
    }
}

// Neighborhood attention, 8x4 query tile per (b, head). 256 threads.
// K and V stored as bf16 in LDS (row stride 40 bf16 = 80 B, b128-aligned);
// Q fp32 in registers; probs fp32 in LDS. V prefetched to regs during QK.
// thread = (q 0..31, r 0..7). LDS = 140*40*2 + 32*49*4 = 17.2 KB.
__global__ __launch_bounds__(256, 5) void nattn_84(
    const float* __restrict__ qkv, float* __restrict__ attn_out,
    float* __restrict__ attn_glob)
{
    __shared__ __align__(16) __bf16 Ks[140 * 40];   // K then V (bf16)
    __shared__ float Ss[32 * 49];                   // probs

    const int bx   = blockIdx.x;
    const int head = bx & 7;
    int t = bx >> 3;
    const int tj = t % 14; t /= 14;
    const int ti = t % 7;
    const int b  = t / 7;
    const int tid = threadIdx.x;

    int base_h = ti * 8 - 3; if (base_h < 0) base_h = 0; if (base_h > Hh - 14) base_h = Hh - 14;
    int base_w = tj * 4 - 3; if (base_w < 0) base_w = 0; if (base_w > Ww - 10) base_w = Ww - 10;

    const int pixb = b * HWsz;
    const int hoff = head * 32;

    // --- stage K (fp32 -> bf16) into LDS: idx over 140 rows x 4 chunks(8 dims) ---
    #pragma unroll
    for (int it = 0; it < 3; ++it) {
        const int idx = tid + it * 256;
        if (idx < 560) {
            const int p = idx >> 2, c = idx & 3;
            const int pix = pixb + (base_h + p / 10) * Ww + base_w + p % 10;
            const float* kp = &qkv[(size_t)pix * 768 + 256 + hoff + c * 8];
            float4 k0 = *(const float4*)kp;
            float4 k1 = *(const float4*)(kp + 4);
            bf16x8 kb = { (__bf16)k0.x, (__bf16)k0.y, (__bf16)k0.z, (__bf16)k0.w,
                          (__bf16)k1.x, (__bf16)k1.y, (__bf16)k1.z, (__bf16)k1.w };
            *(bf16x8*)&Ks[p * 40 + c * 8] = kb;
        }
    }

    const int q  = tid >> 3;         // query in tile
    const int r  = tid & 7;          // phase
    const int qi = ti * 8 + (q >> 2);
    const int qj = tj * 4 + (q & 3);

    float qreg[32];
    {
        const float* qp = &qkv[(size_t)(pixb + qi * Ww + qj) * 768 + hoff];
        #pragma unroll
        for (int c = 0; c < 8; ++c) {
            float4 qv = *(const float4*)(qp + c * 4);
            qreg[c * 4 + 0] = qv.x; qreg[c * 4 + 1] = qv.y;
            qreg[c * 4 + 2] = qv.z; qreg[c * 4 + 3] = qv.w;
        }
    }

    // --- prefetch V (fp32) to registers; converted + written to LDS later ---
    float4 vreg[6];
    #pragma unroll
    for (int it = 0; it < 3; ++it) {
        const int idx = tid + it * 256;
        if (idx < 560) {
            const int p = idx >> 2, c = idx & 3;
            const int pix = pixb + (base_h + p / 10) * Ww + base_w + p % 10;
            const float* vp = &qkv[(size_t)pix * 768 + 512 + hoff + c * 8];
            vreg[it * 2]     = *(const float4*)vp;
            vreg[it * 2 + 1] = *(const float4*)(vp + 4);
        }
    }
    __syncthreads();

    int ih0 = qi - 3; if (ih0 < 0) ih0 = 0; if (ih0 > Hh - 7) ih0 = Hh - 7;
    int iw0 = qj - 3; if (iw0 < 0) iw0 = 0; if (iw0 > Ww - 7) iw0 = Ww - 7;
    const int lh0 = ih0 - base_h, lw0 = iw0 - base_w;

    // --- QK: phase r handles keys k = r, r+8, ... ---
    float sc[7];
    float mx = -1e30f;
    #pragma unroll
    for (int tt = 0; tt < 7; ++tt) {
        const int k = r + 8 * tt;
        if (k < 49) {
            const int krow = (lh0 + k / 7) * 10 + lw0 + k % 7;
            const __bf16* kp = &Ks[krow * 40];
            float acc = 0.f;
            #pragma unroll
            for (int c = 0; c < 4; ++c) {
                bf16x8 kv = *(const bf16x8*)(kp + c * 8);
                #pragma unroll
                for (int j = 0; j < 8; ++j)
                    acc += qreg[c * 8 + j] * (float)kv[j];
            }
            sc[tt] = acc;
            mx = fmaxf(mx, acc);
        }
    }
    mx = fmaxf(mx, __shfl_xor(mx, 1));
    mx = fmaxf(mx, __shfl_xor(mx, 2));
    mx = fmaxf(mx, __shfl_xor(mx, 4));
    float sum = 0.f;
    #pragma unroll
    for (int tt = 0; tt < 7; ++tt) {
        const int k = r + 8 * tt;
        if (k < 49) { sc[tt] = __expf(sc[tt] - mx); sum += sc[tt]; }
    }
    sum += __shfl_xor(sum, 1);
    sum += __shfl_xor(sum, 2);
    sum += __shfl_xor(sum, 4);
    const float inv = 1.f / sum;
    #pragma unroll
    for (int tt = 0; tt < 7; ++tt) {
        const int k = r + 8 * tt;
        if (k < 49) Ss[q * 49 + k] = sc[tt] * inv;
    }
    __syncthreads();   // all K reads + prob writes done

    // --- V regs (fp32) -> bf16 LDS; attn probs -> global ---
    #pragma unroll
    for (int it = 0; it < 3; ++it) {
        const int idx = tid + it * 256;
        if (idx < 560) {
            const int p = idx >> 2, c = idx & 3;
            const float4 v0 = vreg[it * 2], v1 = vreg[it * 2 + 1];
            bf16x8 vb = { (__bf16)v0.x, (__bf16)v0.y, (__bf16)v0.z, (__bf16)v0.w,
                          (__bf16)v1.x, (__bf16)v1.y, (__bf16)v1.z, (__bf16)v1.w };
            *(bf16x8*)&Ks[p * 40 + c * 8] = vb;
        }
    }
    const size_t agbase = (size_t)(b * NHh + head) * HWsz;
    for (int idx = tid; idx < 32 * 49; idx += 256) {
        const int qq = idx / 49, k = idx - qq * 49;
        attn_glob[(agbase + (ti * 8 + (qq >> 2)) * Ww + tj * 4 + (qq & 3)) * 49 + k]
            = Ss[qq * 49 + k];
    }
    __syncthreads();

    // --- PV: thread (q, r): dim chunk rc = r&3 (8 dims), key parity par = r>>2 ---
    const int rc  = r & 3;
    const int par = r >> 2;
    float a[8] = {};
    #pragma unroll
    for (int tt = 0; tt < 25; ++tt) {
        const int k = par + 2 * tt;
        if (k < 49) {
            const float pr = Ss[q * 49 + k];
            const int vrow = (lh0 + k / 7) * 10 + lw0 + k % 7;
            bf16x8 v8 = *(const bf16x8*)&Ks[vrow * 40 + rc * 8];
            #pragma unroll
            for (int j = 0; j < 8; ++j)
                a[j] += pr * (float)v8[j];
        }
    }
    #pragma unroll
    for (int j = 0; j < 8; ++j) a[j] += __shfl_xor(a[j], 4);

    // lane par=0 writes dims [rc*8, rc*8+4), par=1 writes [rc*8+4, rc*8+8)
    float4 o;
    o.x = a[par * 4 + 0]; o.y = a[par * 4 + 1];
    o.z = a[par * 4 + 2]; o.w = a[par * 4 + 3];
    *(float4*)(attn_out + (size_t)(pixb + qi * Ww + qj) * 256 + hoff + rc * 8 + par * 4) = o;
}

extern "C" void kernel_launch(void* const* d_in, const int* in_sizes, int n_in,
                              void* d_out, int out_size, void* d_ws, size_t ws_size,
                              hipStream_t stream)
{
    const float* x      = (const float*)d_in[0];
    const float* w_qk   = (const float*)d_in[1];
    const float* w_v    = (const float*)d_in[2];
    const float* w_proj = (const float*)d_in[3];
    const float* b_proj = (const float*)d_in[4];

    float* out       = (float*)d_out;                    // chunk 0: (B,H,W,C)
    float* attn_glob = out + (size_t)Mtot * Cc;          // chunk 1: (B,NH,H,W,49)

    float* qkv_ws  = (float*)d_ws;                       // M x 768 (q|k|v)
    float* attn_ws = qkv_ws + (size_t)Mtot * 768;        // M x 256

    const float scale = 0.17677669529663687f;            // HD^-0.5

    gemm_bf16<<<dim3(768 / 64, Mtot / 64), 256, 0, stream>>>(
        x, w_qk, w_v, qkv_ws, Cc, 768, 512, 256, scale, nullptr);

    nattn_84<<<Bb * 7 * 14 * NHh, 256, 0, stream>>>(qkv_ws, attn_ws, attn_glob);

    gemm_bf16<<<dim3(256 / 64, Mtot / 64), 256, 0, stream>>>(
        attn_ws, w_proj, w_proj, out, Cc, Cc, 1 << 30, 0, 1.f, b_proj);
}

// Round 6
// 109.140 us; speedup vs baseline: 1.0804x; 1.0369x over previous
//
#include <hip/hip_runtime.h>
#include <math.h>

#define Bb   2
#define Hh   56
#define Ww   56
#define Cc   256
#define NHh  8
#define HDd  32
#define KK   7
#define HWsz (Hh*Ww)
#define Mtot (Bb*Hh*Ww)   // 6272

typedef __bf16 bf16x8 __attribute__((ext_vector_type(8)));
typedef __bf16 bf16x4 __attribute__((ext_vector_type(4)));
typedef float  f32x4  __attribute__((ext_vector_type(4)));

// QKV projection: C[m,n] = sum_k A[m,k]*Wrow(n)[k], A fp32.
// Output row layout (per m): fp32 q[256] | bf16 k[256] | bf16 v[256]  (2 KB).
// cols < 256 -> OutF (fp32, scaled); cols >= 256 -> OutB bf16 at
// m*1024 + 512 + (n-256).
__global__ __launch_bounds__(256) void gemm_qkv(
    const float* __restrict__ A, const float* __restrict__ W0,
    const float* __restrict__ W1, float* __restrict__ OutF,
    __bf16* __restrict__ OutB, float scale)
{
    __shared__ __bf16 As[4096];
    __shared__ __bf16 Bs[4096];

    const int Kdim = 256, n_split = 512;
    const int tid = threadIdx.x;
    const int m0  = blockIdx.y * 64;
    const int n0  = blockIdx.x * 64;

    const int mm = tid >> 2;
    const int q  = tid & 3;
    const float* arow = A + (size_t)(m0 + mm) * Kdim + q * 16;
    const int n_idx = n0 + mm;
    const float* brow = (n_idx < n_split ? W0 + (size_t)n_idx * Kdim
                                         : W1 + (size_t)(n_idx - n_split) * Kdim) + q * 16;

    const int ks_st  = q >> 1;
    const int sub_st = mm >> 4;
    const int row_st = mm & 15;
    const int c0_st  = (q & 1) * 2;
    const int blk_st = ks_st * 4 + sub_st;
    const int off0 = blk_st * 512 + row_st * 32 + ((c0_st ^ (row_st & 3)) * 8);
    const int off1 = blk_st * 512 + row_st * 32 + (((c0_st + 1) ^ (row_st & 3)) * 8);

    const int w    = tid >> 6;
    const int lane = tid & 63;
    const int fr_row = lane & 15;
    const int fr_c   = lane >> 4;
    const int fr_off = fr_row * 32 + ((fr_c ^ (fr_row & 3)) * 8);

    f32x4 acc[4] = {};

    for (int k0 = 0; k0 < Kdim; k0 += 64) {
        float4 a0 = *(const float4*)(arow + k0);
        float4 a1 = *(const float4*)(arow + k0 + 4);
        float4 a2 = *(const float4*)(arow + k0 + 8);
        float4 a3 = *(const float4*)(arow + k0 + 12);
        float4 b0 = *(const float4*)(brow + k0);
        float4 b1 = *(const float4*)(brow + k0 + 4);
        float4 b2 = *(const float4*)(brow + k0 + 8);
        float4 b3 = *(const float4*)(brow + k0 + 12);
        __syncthreads();
        bf16x8 av0 = { (__bf16)a0.x, (__bf16)a0.y, (__bf16)a0.z, (__bf16)a0.w,
                       (__bf16)a1.x, (__bf16)a1.y, (__bf16)a1.z, (__bf16)a1.w };
        bf16x8 av1 = { (__bf16)a2.x, (__bf16)a2.y, (__bf16)a2.z, (__bf16)a2.w,
                       (__bf16)a3.x, (__bf16)a3.y, (__bf16)a3.z, (__bf16)a3.w };
        bf16x8 bv0 = { (__bf16)b0.x, (__bf16)b0.y, (__bf16)b0.z, (__bf16)b0.w,
                       (__bf16)b1.x, (__bf16)b1.y, (__bf16)b1.z, (__bf16)b1.w };
        bf16x8 bv1 = { (__bf16)b2.x, (__bf16)b2.y, (__bf16)b2.z, (__bf16)b2.w,
                       (__bf16)b3.x, (__bf16)b3.y, (__bf16)b3.z, (__bf16)b3.w };
        *(bf16x8*)&As[off0] = av0;
        *(bf16x8*)&As[off1] = av1;
        *(bf16x8*)&Bs[off0] = bv0;
        *(bf16x8*)&Bs[off1] = bv1;
        __syncthreads();
        #pragma unroll
        for (int ks = 0; ks < 2; ++ks) {
            bf16x8 af = *(const bf16x8*)&As[(ks * 4 + w) * 512 + fr_off];
            #pragma unroll
            for (int n = 0; n < 4; ++n) {
                bf16x8 bfr = *(const bf16x8*)&Bs[(ks * 4 + n) * 512 + fr_off];
                acc[n] = __builtin_amdgcn_mfma_f32_16x16x32_bf16(af, bfr, acc[n], 0, 0, 0);
            }
        }
    }

    // epilogue: col = fr_row + n*16 + n0, row = m0 + w*16 + fr_c*4 + r
    if (n0 < 256) {   // q region, fp32, scaled
        #pragma unroll
        for (int n = 0; n < 4; ++n) {
            const int gcol = n0 + n * 16 + fr_row;
            #pragma unroll
            for (int r = 0; r < 4; ++r) {
                const int grow = m0 + w * 16 + fr_c * 4 + r;
                OutF[(size_t)grow * 512 + gcol] = acc[n][r] * scale;
            }
        }
    } else {          // k/v region, bf16
        #pragma unroll
        for (int n = 0; n < 4; ++n) {
            const int gcol = n0 + n * 16 + fr_row;
            #pragma unroll
            for (int r = 0; r < 4; ++r) {
                const int grow = m0 + w * 16 + fr_c * 4 + r;
                OutB[(size_t)grow * 1024 + 512 + (gcol - 256)] = (__bf16)acc[n][r];
            }
        }
    }
}

// Output projection: A bf16 (M x 256), W fp32 (256 x 256), out fp32 + bias.
__global__ __launch_bounds__(256) void gemm_a16(
    const __bf16* __restrict__ A, const float* __restrict__ W,
    float* __restrict__ Cout, const float* __restrict__ bias)
{
    __shared__ __bf16 As[4096];
    __shared__ __bf16 Bs[4096];

    const int Kdim = 256, N = 256;
    const int tid = threadIdx.x;
    const int m0  = blockIdx.y * 64;
    const int n0  = blockIdx.x * 64;

    const int mm = tid >> 2;
    const int q  = tid & 3;
    const __bf16* arow = A + (size_t)(m0 + mm) * Kdim + q * 16;
    const float*  brow = W + (size_t)(n0 + mm) * Kdim + q * 16;

    const int ks_st  = q >> 1;
    const int sub_st = mm >> 4;
    const int row_st = mm & 15;
    const int c0_st  = (q & 1) * 2;
    const int blk_st = ks_st * 4 + sub_st;
    const int off0 = blk_st * 512 + row_st * 32 + ((c0_st ^ (row_st & 3)) * 8);
    const int off1 = blk_st * 512 + row_st * 32 + (((c0_st + 1) ^ (row_st & 3)) * 8);

    const int w    = tid >> 6;
    const int lane = tid & 63;
    const int fr_row = lane & 15;
    const int fr_c   = lane >> 4;
    const int fr_off = fr_row * 32 + ((fr_c ^ (fr_row & 3)) * 8);

    f32x4 acc[4] = {};

    for (int k0 = 0; k0 < Kdim; k0 += 64) {
        bf16x8 av0 = *(const bf16x8*)(arow + k0);
        bf16x8 av1 = *(const bf16x8*)(arow + k0 + 8);
        float4 b0 = *(const float4*)(brow + k0);
        float4 b1 = *(const float4*)(brow + k0 + 4);
        float4 b2 = *(const float4*)(brow + k0 + 8);
        float4 b3 = *(const float4*)(brow + k0 + 12);
        __syncthreads();
        bf16x8 bv0 = { (__bf16)b0.x, (__bf16)b0.y, (__bf16)b0.z, (__bf16)b0.w,
                       (__bf16)b1.x, (__bf16)b1.y, (__bf16)b1.z, (__bf16)b1.w };
        bf16x8 bv1 = { (__bf16)b2.x, (__bf16)b2.y, (__bf16)b2.z, (__bf16)b2.w,
                       (__bf16)b3.x, (__bf16)b3.y, (__bf16)b3.z, (__bf16)b3.w };
        *(bf16x8*)&As[off0] = av0;
        *(bf16x8*)&As[off1] = av1;
        *(bf16x8*)&Bs[off0] = bv0;
        *(bf16x8*)&Bs[off1] = bv1;
        __syncthreads();
        #pragma unroll
        for (int ks = 0; ks < 2; ++ks) {
            bf16x8 af = *(const bf16x8*)&As[(ks * 4 + w) * 512 + fr_off];
            #pragma unroll
            for (int n = 0; n < 4; ++n) {
                bf16x8 bfr = *(const bf16x8*)&Bs[(ks * 4 + n) * 512 + fr_off];
                acc[n] = __builtin_amdgcn_mfma_f32_16x16x32_bf16(af, bfr, acc[n], 0, 0, 0);
            }
        }
    }

    #pragma unroll
    for (int n = 0; n < 4; ++n) {
        const int gcol = n0 + n * 16 + fr_row;
        const float bs_ = bias[gcol];
        #pragma unroll
        for (int r = 0; r < 4; ++r) {
            const int grow = m0 + w * 16 + fr_c * 4 + r;
            Cout[(size_t)grow * N + gcol] = acc[n][r] + bs_;
        }
    }
}

// Neighborhood attention, 8x4 query tile per (b, head). 256 threads.
// qkv row layout: fp32 q[256] | bf16 k[256] | bf16 v[256]  (2 KB / pixel).
// K/V loaded as bf16 (no convert), Q fp32 regs, probs fp32 LDS, fp32 accum.
__global__ __launch_bounds__(256, 5) void nattn_84(
    const float* __restrict__ qkv, __bf16* __restrict__ attn_out,
    float* __restrict__ attn_glob)
{
    __shared__ __align__(16) __bf16 Ks[140 * 40];   // K then V (bf16)
    __shared__ float Ss[32 * 49];                   // probs

    const float*  qf = qkv;
    const __bf16* qb = (const __bf16*)qkv;

    const int bx   = blockIdx.x;
    const int head = bx & 7;
    int t = bx >> 3;
    const int tj = t % 14; t /= 14;
    const int ti = t % 7;
    const int b  = t / 7;
    const int tid = threadIdx.x;

    int base_h = ti * 8 - 3; if (base_h < 0) base_h = 0; if (base_h > Hh - 14) base_h = Hh - 14;
    int base_w = tj * 4 - 3; if (base_w < 0) base_w = 0; if (base_w > Ww - 10) base_w = Ww - 10;

    const int pixb = b * HWsz;
    const int hoff = head * 32;

    // --- stage K (bf16 direct) into LDS: 140 rows x 4 chunks of 8 dims ---
    #pragma unroll
    for (int it = 0; it < 3; ++it) {
        const int idx = tid + it * 256;
        if (idx < 560) {
            const int p = idx >> 2, c = idx & 3;
            const int pix = pixb + (base_h + p / 10) * Ww + base_w + p % 10;
            *(bf16x8*)&Ks[p * 40 + c * 8] =
                *(const bf16x8*)&qb[(size_t)pix * 1024 + 512 + hoff + c * 8];
        }
    }

    const int q  = tid >> 3;
    const int r  = tid & 7;
    const int qi = ti * 8 + (q >> 2);
    const int qj = tj * 4 + (q & 3);

    float qreg[32];
    {
        const float* qp = &qf[(size_t)(pixb + qi * Ww + qj) * 512 + hoff];
        #pragma unroll
        for (int c = 0; c < 8; ++c) {
            float4 qv = *(const float4*)(qp + c * 4);
            qreg[c * 4 + 0] = qv.x; qreg[c * 4 + 1] = qv.y;
            qreg[c * 4 + 2] = qv.z; qreg[c * 4 + 3] = qv.w;
        }
    }

    // --- prefetch V (bf16) to registers ---
    bf16x8 vreg[3];
    #pragma unroll
    for (int it = 0; it < 3; ++it) {
        const int idx = tid + it * 256;
        if (idx < 560) {
            const int p = idx >> 2, c = idx & 3;
            const int pix = pixb + (base_h + p / 10) * Ww + base_w + p % 10;
            vreg[it] = *(const bf16x8*)&qb[(size_t)pix * 1024 + 768 + hoff + c * 8];
        }
    }
    __syncthreads();

    int ih0 = qi - 3; if (ih0 < 0) ih0 = 0; if (ih0 > Hh - 7) ih0 = Hh - 7;
    int iw0 = qj - 3; if (iw0 < 0) iw0 = 0; if (iw0 > Ww - 7) iw0 = Ww - 7;
    const int lh0 = ih0 - base_h, lw0 = iw0 - base_w;

    // --- QK ---
    float sc[7];
    float mx = -1e30f;
    #pragma unroll
    for (int tt = 0; tt < 7; ++tt) {
        const int k = r + 8 * tt;
        if (k < 49) {
            const int krow = (lh0 + k / 7) * 10 + lw0 + k % 7;
            const __bf16* kp = &Ks[krow * 40];
            float acc = 0.f;
            #pragma unroll
            for (int c = 0; c < 4; ++c) {
                bf16x8 kv = *(const bf16x8*)(kp + c * 8);
                #pragma unroll
                for (int j = 0; j < 8; ++j)
                    acc += qreg[c * 8 + j] * (float)kv[j];
            }
            sc[tt] = acc;
            mx = fmaxf(mx, acc);
        }
    }
    mx = fmaxf(mx, __shfl_xor(mx, 1));
    mx = fmaxf(mx, __shfl_xor(mx, 2));
    mx = fmaxf(mx, __shfl_xor(mx, 4));
    float sum = 0.f;
    #pragma unroll
    for (int tt = 0; tt < 7; ++tt) {
        const int k = r + 8 * tt;
        if (k < 49) { sc[tt] = __expf(sc[tt] - mx); sum += sc[tt]; }
    }
    sum += __shfl_xor(sum, 1);
    sum += __shfl_xor(sum, 2);
    sum += __shfl_xor(sum, 4);
    const float inv = 1.f / sum;
    #pragma unroll
    for (int tt = 0; tt < 7; ++tt) {
        const int k = r + 8 * tt;
        if (k < 49) Ss[q * 49 + k] = sc[tt] * inv;
    }
    __syncthreads();

    // --- V regs -> LDS; attn probs -> global ---
    #pragma unroll
    for (int it = 0; it < 3; ++it) {
        const int idx = tid + it * 256;
        if (idx < 560) {
            const int p = idx >> 2, c = idx & 3;
            *(bf16x8*)&Ks[p * 40 + c * 8] = vreg[it];
        }
    }
    const size_t agbase = (size_t)(b * NHh + head) * HWsz;
    for (int idx = tid; idx < 32 * 49; idx += 256) {
        const int qq = idx / 49, k = idx - qq * 49;
        attn_glob[(agbase + (ti * 8 + (qq >> 2)) * Ww + tj * 4 + (qq & 3)) * 49 + k]
            = Ss[qq * 49 + k];
    }
    __syncthreads();

    // --- PV: dim chunk rc = r&3 (8 dims), key parity par = r>>2 ---
    const int rc  = r & 3;
    const int par = r >> 2;
    float a[8] = {};
    #pragma unroll
    for (int tt = 0; tt < 25; ++tt) {
        const int k = par + 2 * tt;
        if (k < 49) {
            const float pr = Ss[q * 49 + k];
            const int vrow = (lh0 + k / 7) * 10 + lw0 + k % 7;
            bf16x8 v8 = *(const bf16x8*)&Ks[vrow * 40 + rc * 8];
            #pragma unroll
            for (int j = 0; j < 8; ++j)
                a[j] += pr * (float)v8[j];
        }
    }
    #pragma unroll
    for (int j = 0; j < 8; ++j) a[j] += __shfl_xor(a[j], 4);

    // lane par writes 4 dims as bf16
    bf16x4 o = { (__bf16)a[par * 4 + 0], (__bf16)a[par * 4 + 1],
                 (__bf16)a[par * 4 + 2], (__bf16)a[par * 4 + 3] };
    *(bf16x4*)(attn_out + (size_t)(pixb + qi * Ww + qj) * 256 + hoff + rc * 8 + par * 4) = o;
}

extern "C" void kernel_launch(void* const* d_in, const int* in_sizes, int n_in,
                              void* d_out, int out_size, void* d_ws, size_t ws_size,
                              hipStream_t stream)
{
    const float* x      = (const float*)d_in[0];
    const float* w_qk   = (const float*)d_in[1];
    const float* w_v    = (const float*)d_in[2];
    const float* w_proj = (const float*)d_in[3];
    const float* b_proj = (const float*)d_in[4];

    float* out       = (float*)d_out;                    // chunk 0: (B,H,W,C)
    float* attn_glob = out + (size_t)Mtot * Cc;          // chunk 1: (B,NH,H,W,49)

    float*  qkv_ws  = (float*)d_ws;                      // M x 2KB rows (q f32 | k bf16 | v bf16)
    __bf16* attn_ws = (__bf16*)(qkv_ws + (size_t)Mtot * 512);  // M x 256 bf16

    const float scale = 0.17677669529663687f;            // HD^-0.5

    gemm_qkv<<<dim3(768 / 64, Mtot / 64), 256, 0, stream>>>(
        x, w_qk, w_v, qkv_ws, (__bf16*)qkv_ws, scale);

    nattn_84<<<Bb * 7 * 14 * NHh, 256, 0, stream>>>(qkv_ws, attn_ws, attn_glob);

    gemm_a16<<<dim3(256 / 64, Mtot / 64), 256, 0, stream>>>(
        attn_ws, w_proj, out, b_proj);
}

// Round 7
// 102.745 us; speedup vs baseline: 1.1477x; 1.0622x over previous
//
#include <hip/hip_runtime.h>
#include <math.h>

#define Bb   2
#define Hh   56
#define Ww   56
#define Cc   256
#define NHh  8
#define HDd  32
#define KK   7
#define HWsz (Hh*Ww)
#define Mtot (Bb*Hh*Ww)   // 6272

typedef __bf16 bf16x8 __attribute__((ext_vector_type(8)));
typedef __bf16 bf16x4 __attribute__((ext_vector_type(4)));
typedef float  f32x4  __attribute__((ext_vector_type(4)));

// One-shot fp32 -> bf16 conversion of x, w_qk, w_v, w_proj.
// Segments (in 8-element chunks): x 200704 | w_qk 16384 | w_v 8192 | w_proj 8192.
__global__ __launch_bounds__(256) void prep_bf16(
    const float* __restrict__ x, const float* __restrict__ wqk,
    const float* __restrict__ wv, const float* __restrict__ wp,
    __bf16* __restrict__ xb, __bf16* __restrict__ wallb, __bf16* __restrict__ wpb)
{
    const int t = blockIdx.x * 256 + threadIdx.x;   // 912*256 = 233472 chunks
    const float* src; __bf16* dst; int off;
    if (t < 200704)      { src = x;   dst = xb;             off = t; }
    else if (t < 217088) { src = wqk; dst = wallb;          off = t - 200704; }
    else if (t < 225280) { src = wv;  dst = wallb + 131072; off = t - 217088; }
    else                 { src = wp;  dst = wpb;            off = t - 225280; }
    const int e = off * 8;
    float4 a = *(const float4*)(src + e);
    float4 b = *(const float4*)(src + e + 4);
    bf16x8 o = { (__bf16)a.x, (__bf16)a.y, (__bf16)a.z, (__bf16)a.w,
                 (__bf16)b.x, (__bf16)b.y, (__bf16)b.z, (__bf16)b.w };
    *(bf16x8*)(dst + e) = o;
}

// QKV projection, pure bf16: A (M x 256 bf16) @ wallb^T (768 x 256 bf16).
// Out: qkv bf16 rows of 768 (q scaled | k | v). 64x64 tile, BK=64, 4 waves.
__global__ __launch_bounds__(256) void gemm_qkv_b(
    const __bf16* __restrict__ A, const __bf16* __restrict__ Wall,
    __bf16* __restrict__ Out, float scale)
{
    __shared__ __bf16 As[4096];
    __shared__ __bf16 Bs[4096];

    const int Kdim = 256;
    const int tid = threadIdx.x;
    const int m0  = blockIdx.y * 64;
    const int n0  = blockIdx.x * 64;

    const int mm = tid >> 2;
    const int q  = tid & 3;
    const __bf16* arow = A    + (size_t)(m0 + mm) * Kdim + q * 16;
    const __bf16* brow = Wall + (size_t)(n0 + mm) * Kdim + q * 16;

    const int ks_st  = q >> 1;
    const int sub_st = mm >> 4;
    const int row_st = mm & 15;
    const int c0_st  = (q & 1) * 2;
    const int blk_st = ks_st * 4 + sub_st;
    const int off0 = blk_st * 512 + row_st * 32 + ((c0_st ^ (row_st & 3)) * 8);
    const int off1 = blk_st * 512 + row_st * 32 + (((c0_st + 1) ^ (row_st & 3)) * 8);

    const int w    = tid >> 6;
    const int lane = tid & 63;
    const int fr_row = lane & 15;
    const int fr_c   = lane >> 4;
    const int fr_off = fr_row * 32 + ((fr_c ^ (fr_row & 3)) * 8);

    f32x4 acc[4] = {};

    for (int k0 = 0; k0 < Kdim; k0 += 64) {
        bf16x8 av0 = *(const bf16x8*)(arow + k0);
        bf16x8 av1 = *(const bf16x8*)(arow + k0 + 8);
        bf16x8 bv0 = *(const bf16x8*)(brow + k0);
        bf16x8 bv1 = *(const bf16x8*)(brow + k0 + 8);
        __syncthreads();
        *(bf16x8*)&As[off0] = av0;
        *(bf16x8*)&As[off1] = av1;
        *(bf16x8*)&Bs[off0] = bv0;
        *(bf16x8*)&Bs[off1] = bv1;
        __syncthreads();
        #pragma unroll
        for (int ks = 0; ks < 2; ++ks) {
            bf16x8 af = *(const bf16x8*)&As[(ks * 4 + w) * 512 + fr_off];
            #pragma unroll
            for (int n = 0; n < 4; ++n) {
                bf16x8 bfr = *(const bf16x8*)&Bs[(ks * 4 + n) * 512 + fr_off];
                acc[n] = __builtin_amdgcn_mfma_f32_16x16x32_bf16(af, bfr, acc[n], 0, 0, 0);
            }
        }
    }

    #pragma unroll
    for (int n = 0; n < 4; ++n) {
        const int gcol = n0 + n * 16 + fr_row;
        const float sc_ = (gcol < 256) ? scale : 1.f;
        #pragma unroll
        for (int r = 0; r < 4; ++r) {
            const int grow = m0 + w * 16 + fr_c * 4 + r;
            Out[(size_t)grow * 768 + gcol] = (__bf16)(acc[n][r] * sc_);
        }
    }
}

// Output projection, bf16 operands: attn (M x 256 bf16) @ wpb^T; fp32 out + bias.
__global__ __launch_bounds__(256) void gemm_proj_b(
    const __bf16* __restrict__ A, const __bf16* __restrict__ W,
    float* __restrict__ Cout, const float* __restrict__ bias)
{
    __shared__ __bf16 As[4096];
    __shared__ __bf16 Bs[4096];

    const int Kdim = 256, N = 256;
    const int tid = threadIdx.x;
    const int m0  = blockIdx.y * 64;
    const int n0  = blockIdx.x * 64;

    const int mm = tid >> 2;
    const int q  = tid & 3;
    const __bf16* arow = A + (size_t)(m0 + mm) * Kdim + q * 16;
    const __bf16* brow = W + (size_t)(n0 + mm) * Kdim + q * 16;

    const int ks_st  = q >> 1;
    const int sub_st = mm >> 4;
    const int row_st = mm & 15;
    const int c0_st  = (q & 1) * 2;
    const int blk_st = ks_st * 4 + sub_st;
    const int off0 = blk_st * 512 + row_st * 32 + ((c0_st ^ (row_st & 3)) * 8);
    const int off1 = blk_st * 512 + row_st * 32 + (((c0_st + 1) ^ (row_st & 3)) * 8);

    const int w    = tid >> 6;
    const int lane = tid & 63;
    const int fr_row = lane & 15;
    const int fr_c   = lane >> 4;
    const int fr_off = fr_row * 32 + ((fr_c ^ (fr_row & 3)) * 8);

    f32x4 acc[4] = {};

    for (int k0 = 0; k0 < Kdim; k0 += 64) {
        bf16x8 av0 = *(const bf16x8*)(arow + k0);
        bf16x8 av1 = *(const bf16x8*)(arow + k0 + 8);
        bf16x8 bv0 = *(const bf16x8*)(brow + k0);
        bf16x8 bv1 = *(const bf16x8*)(brow + k0 + 8);
        __syncthreads();
        *(bf16x8*)&As[off0] = av0;
        *(bf16x8*)&As[off1] = av1;
        *(bf16x8*)&Bs[off0] = bv0;
        *(bf16x8*)&Bs[off1] = bv1;
        __syncthreads();
        #pragma unroll
        for (int ks = 0; ks < 2; ++ks) {
            bf16x8 af = *(const bf16x8*)&As[(ks * 4 + w) * 512 + fr_off];
            #pragma unroll
            for (int n = 0; n < 4; ++n) {
                bf16x8 bfr = *(const bf16x8*)&Bs[(ks * 4 + n) * 512 + fr_off];
                acc[n] = __builtin_amdgcn_mfma_f32_16x16x32_bf16(af, bfr, acc[n], 0, 0, 0);
            }
        }
    }

    #pragma unroll
    for (int n = 0; n < 4; ++n) {
        const int gcol = n0 + n * 16 + fr_row;
        const float bs_ = bias[gcol];
        #pragma unroll
        for (int r = 0; r < 4; ++r) {
            const int grow = m0 + w * 16 + fr_c * 4 + r;
            Cout[(size_t)grow * N + gcol] = acc[n][r] + bs_;
        }
    }
}

// Neighborhood attention, 8x4 query tile per (b, head). 256 threads.
// qkv: bf16 rows of 768 (q | k | v). Q -> fp32 regs; K/V bf16 LDS;
// probs fp32 LDS; fp32 accum. LDS = 140*40*2 + 32*49*4 = 17.2 KB.
__global__ __launch_bounds__(256, 5) void nattn_84(
    const __bf16* __restrict__ qkv, __bf16* __restrict__ attn_out,
    float* __restrict__ attn_glob)
{
    __shared__ __align__(16) __bf16 Ks[140 * 40];   // K then V (bf16)
    __shared__ float Ss[32 * 49];                   // probs

    const int bx   = blockIdx.x;
    const int head = bx & 7;
    int t = bx >> 3;
    const int tj = t % 14; t /= 14;
    const int ti = t % 7;
    const int b  = t / 7;
    const int tid = threadIdx.x;

    int base_h = ti * 8 - 3; if (base_h < 0) base_h = 0; if (base_h > Hh - 14) base_h = Hh - 14;
    int base_w = tj * 4 - 3; if (base_w < 0) base_w = 0; if (base_w > Ww - 10) base_w = Ww - 10;

    const int pixb = b * HWsz;
    const int hoff = head * 32;

    // --- stage K into LDS: 140 rows x 4 chunks of 8 dims ---
    #pragma unroll
    for (int it = 0; it < 3; ++it) {
        const int idx = tid + it * 256;
        if (idx < 560) {
            const int p = idx >> 2, c = idx & 3;
            const int pix = pixb + (base_h + p / 10) * Ww + base_w + p % 10;
            *(bf16x8*)&Ks[p * 40 + c * 8] =
                *(const bf16x8*)&qkv[(size_t)pix * 768 + 256 + hoff + c * 8];
        }
    }

    const int q  = tid >> 3;
    const int r  = tid & 7;
    const int qi = ti * 8 + (q >> 2);
    const int qj = tj * 4 + (q & 3);

    float qreg[32];
    {
        const __bf16* qp = &qkv[(size_t)(pixb + qi * Ww + qj) * 768 + hoff];
        #pragma unroll
        for (int c = 0; c < 4; ++c) {
            bf16x8 qv = *(const bf16x8*)(qp + c * 8);
            #pragma unroll
            for (int j = 0; j < 8; ++j) qreg[c * 8 + j] = (float)qv[j];
        }
    }

    // --- prefetch V to registers ---
    bf16x8 vreg[3];
    #pragma unroll
    for (int it = 0; it < 3; ++it) {
        const int idx = tid + it * 256;
        if (idx < 560) {
            const int p = idx >> 2, c = idx & 3;
            const int pix = pixb + (base_h + p / 10) * Ww + base_w + p % 10;
            vreg[it] = *(const bf16x8*)&qkv[(size_t)pix * 768 + 512 + hoff + c * 8];
        }
    }
    __syncthreads();

    int ih0 = qi - 3; if (ih0 < 0) ih0 = 0; if (ih0 > Hh - 7) ih0 = Hh - 7;
    int iw0 = qj - 3; if (iw0 < 0) iw0 = 0; if (iw0 > Ww - 7) iw0 = Ww - 7;
    const int lh0 = ih0 - base_h, lw0 = iw0 - base_w;

    // --- QK ---
    float sc[7];
    float mx = -1e30f;
    #pragma unroll
    for (int tt = 0; tt < 7; ++tt) {
        const int k = r + 8 * tt;
        if (k < 49) {
            const int krow = (lh0 + k / 7) * 10 + lw0 + k % 7;
            const __bf16* kp = &Ks[krow * 40];
            float acc = 0.f;
            #pragma unroll
            for (int c = 0; c < 4; ++c) {
                bf16x8 kv = *(const bf16x8*)(kp + c * 8);
                #pragma unroll
                for (int j = 0; j < 8; ++j)
                    acc += qreg[c * 8 + j] * (float)kv[j];
            }
            sc[tt] = acc;
            mx = fmaxf(mx, acc);
        }
    }
    mx = fmaxf(mx, __shfl_xor(mx, 1));
    mx = fmaxf(mx, __shfl_xor(mx, 2));
    mx = fmaxf(mx, __shfl_xor(mx, 4));
    float sum = 0.f;
    #pragma unroll
    for (int tt = 0; tt < 7; ++tt) {
        const int k = r + 8 * tt;
        if (k < 49) { sc[tt] = __expf(sc[tt] - mx); sum += sc[tt]; }
    }
    sum += __shfl_xor(sum, 1);
    sum += __shfl_xor(sum, 2);
    sum += __shfl_xor(sum, 4);
    const float inv = 1.f / sum;
    #pragma unroll
    for (int tt = 0; tt < 7; ++tt) {
        const int k = r + 8 * tt;
        if (k < 49) Ss[q * 49 + k] = sc[tt] * inv;
    }
    __syncthreads();

    // --- V regs -> LDS; attn probs -> global ---
    #pragma unroll
    for (int it = 0; it < 3; ++it) {
        const int idx = tid + it * 256;
        if (idx < 560) {
            const int p = idx >> 2, c = idx & 3;
            *(bf16x8*)&Ks[p * 40 + c * 8] = vreg[it];
        }
    }
    const size_t agbase = (size_t)(b * NHh + head) * HWsz;
    for (int idx = tid; idx < 32 * 49; idx += 256) {
        const int qq = idx / 49, k = idx - qq * 49;
        attn_glob[(agbase + (ti * 8 + (qq >> 2)) * Ww + tj * 4 + (qq & 3)) * 49 + k]
            = Ss[qq * 49 + k];
    }
    __syncthreads();

    // --- PV: dim chunk rc = r&3 (8 dims), key parity par = r>>2 ---
    const int rc  = r & 3;
    const int par = r >> 2;
    float a[8] = {};
    #pragma unroll
    for (int tt = 0; tt < 25; ++tt) {
        const int k = par + 2 * tt;
        if (k < 49) {
            const float pr = Ss[q * 49 + k];
            const int vrow = (lh0 + k / 7) * 10 + lw0 + k % 7;
            bf16x8 v8 = *(const bf16x8*)&Ks[vrow * 40 + rc * 8];
            #pragma unroll
            for (int j = 0; j < 8; ++j)
                a[j] += pr * (float)v8[j];
        }
    }
    #pragma unroll
    for (int j = 0; j < 8; ++j) a[j] += __shfl_xor(a[j], 4);

    bf16x4 o = { (__bf16)a[par * 4 + 0], (__bf16)a[par * 4 + 1],
                 (__bf16)a[par * 4 + 2], (__bf16)a[par * 4 + 3] };
    *(bf16x4*)(attn_out + (size_t)(pixb + qi * Ww + qj) * 256 + hoff + rc * 8 + par * 4) = o;
}

extern "C" void kernel_launch(void* const* d_in, const int* in_sizes, int n_in,
                              void* d_out, int out_size, void* d_ws, size_t ws_size,
                              hipStream_t stream)
{
    const float* x      = (const float*)d_in[0];
    const float* w_qk   = (const float*)d_in[1];
    const float* w_v    = (const float*)d_in[2];
    const float* w_proj = (const float*)d_in[3];
    const float* b_proj = (const float*)d_in[4];

    float* out       = (float*)d_out;                    // chunk 0: (B,H,W,C)
    float* attn_glob = out + (size_t)Mtot * Cc;          // chunk 1: (B,NH,H,W,49)

    __bf16* xb      = (__bf16*)d_ws;                     // M x 256
    __bf16* wallb   = xb + (size_t)Mtot * 256;           // 768 x 256 (qk | v)
    __bf16* wpb     = wallb + 768 * 256;                 // 256 x 256
    __bf16* qkv_ws  = wpb + 256 * 256;                   // M x 768 (q|k|v)
    __bf16* attn_ws = qkv_ws + (size_t)Mtot * 768;       // M x 256

    const float scale = 0.17677669529663687f;            // HD^-0.5

    prep_bf16<<<912, 256, 0, stream>>>(x, w_qk, w_v, w_proj, xb, wallb, wpb);

    gemm_qkv_b<<<dim3(768 / 64, Mtot / 64), 256, 0, stream>>>(
        xb, wallb, qkv_ws, scale);

    nattn_84<<<Bb * 7 * 14 * NHh, 256, 0, stream>>>(qkv_ws, attn_ws, attn_glob);

    gemm_proj_b<<<dim3(256 / 64, Mtot / 64), 256, 0, stream>>>(
        attn_ws, wpb, out, b_proj);
}